// Round 1
// baseline (488.169 us; speedup 1.0000x reference)
//
#include <hip/hip_runtime.h>
#include <hip/hip_bf16.h>
#include <cstdint>

// ---------------- problem dims ----------------
#define BS 8
#define SEQ 2048
#define HDIM 1024
#define NH 16
#define HD 64
#define M_ROWS (BS * SEQ)   // 16384
#define N_COLS (2 * HDIM)   // 2048  (cols 0..1023 = K1, 1024..2047 = V1)
#define KDIM HDIM           // 1024

#define DELTA 0.025f
#define FLAG_CAP 32768

// ---------------- workspace layout (bytes) ----------------
#define OFF_A      ((size_t)0)           // bf16 A [M,K]            33,554,432
#define OFF_BT     ((size_t)33554432)    // bf16 Bt [N,K]            4,194,304
#define OFF_BTK    ((size_t)37748736)    // f32 K1_w^T [1024,1024]   4,194,304
#define OFF_BIAS   ((size_t)41943040)    // f32 [2048]                   8,192
#define OFF_C      ((size_t)41951232)    // f32 C [M,N]            134,217,728
#define OFF_VALID  ((size_t)176168960)   // u8 [BS][NH][SEQ]           262,144
#define OFF_MAPS   ((size_t)176431104)   // ushort4 [BS][SEQ][NH]    2,097,152
#define OFF_FCNT   ((size_t)178528256)   // int
#define OFF_FLIST  ((size_t)178528512)   // int[FLAG_CAP]

typedef __attribute__((ext_vector_type(8))) __bf16 bf16x8;
typedef __attribute__((ext_vector_type(4))) float f32x4;

// float -> bf16 bits, round-to-nearest-even (inputs are finite)
__device__ __forceinline__ unsigned short f2bf(float f) {
    unsigned int x = __builtin_bit_cast(unsigned int, f);
    unsigned int r = x + 0x7fffu + ((x >> 16) & 1u);
    return (unsigned short)(r >> 16);
}

// async 16B global -> LDS (dest = wave-uniform LDS base + lane*16)
__device__ __forceinline__ void g2l16(const void* gp, void* lp) {
    __builtin_amdgcn_global_load_lds(
        (__attribute__((address_space(1))) void*)(void*)gp,
        (__attribute__((address_space(3))) void*)lp, 16, 0, 0);
}

// ---------------- prep kernels ----------------
__global__ void zero_cnt_kernel(int* p) { *p = 0; }

__global__ __launch_bounds__(256) void cvt_hs_kernel(const float4* __restrict__ in,
                                                     ushort4* __restrict__ outp) {
    int i = blockIdx.x * 256 + threadIdx.x;   // 4,194,304 total
    float4 v = in[i];
    ushort4 o;
    o.x = f2bf(v.x); o.y = f2bf(v.y); o.z = f2bf(v.z); o.w = f2bf(v.w);
    outp[i] = o;
}

// transpose W [K=1024][N=1024] -> Bt[n][k] (bf16); also BtK f32 for K1 (z==0)
__global__ __launch_bounds__(256) void cvt_w_kernel(const float* __restrict__ K1w,
                                                    const float* __restrict__ V1w,
                                                    unsigned short* __restrict__ Bt,
                                                    float* __restrict__ BtK) {
    __shared__ float tile[32][33];
    const float* W = blockIdx.z ? V1w : K1w;
    int tn = blockIdx.x, tk = blockIdx.y;
    int t = threadIdx.x;
    int r = t >> 3;            // 0..31
    int c4 = (t & 7) * 4;      // 0,4,..,28
    const float4 v = *(const float4*)&W[(size_t)(tk * 32 + r) * 1024 + tn * 32 + c4];
    tile[r][c4 + 0] = v.x; tile[r][c4 + 1] = v.y; tile[r][c4 + 2] = v.z; tile[r][c4 + 3] = v.w;
    __syncthreads();
    int n = tn * 32 + r;
    int k = tk * 32 + c4;
    float f0 = tile[c4 + 0][r], f1 = tile[c4 + 1][r], f2 = tile[c4 + 2][r], f3 = tile[c4 + 3][r];
    size_t obase = ((size_t)blockIdx.z * 1024 + n) * 1024 + k;
    ushort4 o; o.x = f2bf(f0); o.y = f2bf(f1); o.z = f2bf(f2); o.w = f2bf(f3);
    *(ushort4*)&Bt[obase] = o;
    if (blockIdx.z == 0) {
        *(float4*)&BtK[(size_t)n * 1024 + k] = make_float4(f0, f1, f2, f3);
    }
}

__global__ void cvt_bias_kernel(const float* __restrict__ K1b, const float* __restrict__ V1b,
                                float* __restrict__ bias) {
    int i = blockIdx.x * 256 + threadIdx.x;   // 2048 total
    bias[i] = (i < 1024) ? K1b[i] : V1b[i - 1024];
}

// ---------------- GEMM (m97 pattern): C = relu(A @ Bt^T + bias) ----------------
// A [M,K] bf16, Bt [N,K] bf16, C [M,N] f32. 128x128 tile, BK=32, 4 waves 2x2.
__global__ __launch_bounds__(256) void gemm_kernel(const unsigned short* __restrict__ Abf,
                                                   const unsigned short* __restrict__ Btbf,
                                                   const float* __restrict__ bias,
                                                   float* __restrict__ C) {
    constexpr int K = KDIM, N = N_COLS, BK = 32;
    __shared__ unsigned short As[128 * BK];   // row-major [128][32]
    __shared__ unsigned short Bs[128 * BK];
    const int t = threadIdx.x;
    const int wave = t >> 6, lane = t & 63;
    const int wm = wave >> 1, wn = wave & 1;
    const int l16 = lane & 15, quad = lane >> 4;
    const int m0 = blockIdx.y * 128, n0 = blockIdx.x * 128;

    f32x4 zero4 = {0.f, 0.f, 0.f, 0.f};
    f32x4 acc[4][4];
#pragma unroll
    for (int i = 0; i < 4; i++)
#pragma unroll
        for (int j = 0; j < 4; j++) acc[i][j] = zero4;

    const int srow = t >> 2;          // 0..63
    const int sk = (t & 3) * 8;       // k element offset of this lane's 16B
    const unsigned short* gA = Abf + (size_t)(m0 + srow) * K + sk;
    const unsigned short* gB = Btbf + (size_t)(n0 + srow) * K + sk;
    char* lAs = (char*)As + (size_t)wave * 1024;
    char* lBs = (char*)Bs + (size_t)wave * 1024;

    for (int k0 = 0; k0 < K; k0 += BK) {
        g2l16(gA + k0, lAs);
        g2l16(gA + (size_t)64 * K + k0, lAs + 4096);
        g2l16(gB + k0, lBs);
        g2l16(gB + (size_t)64 * K + k0, lBs + 4096);
        __syncthreads();   // drains global_load_lds (vmcnt) + barrier
        bf16x8 af[4], bfr[4];
#pragma unroll
        for (int mt = 0; mt < 4; mt++)
            af[mt] = *(const bf16x8*)&As[(wm * 64 + mt * 16 + l16) * BK + quad * 8];
#pragma unroll
        for (int nt = 0; nt < 4; nt++)
            bfr[nt] = *(const bf16x8*)&Bs[(wn * 64 + nt * 16 + l16) * BK + quad * 8];
#pragma unroll
        for (int mt = 0; mt < 4; mt++)
#pragma unroll
            for (int nt = 0; nt < 4; nt++)
                acc[mt][nt] = __builtin_amdgcn_mfma_f32_16x16x32_bf16(af[mt], bfr[nt], acc[mt][nt], 0, 0, 0);
        __syncthreads();
    }
    // epilogue: bias + relu, f32 store. C/D: row=quad*4+reg, col=l16
#pragma unroll
    for (int mt = 0; mt < 4; mt++) {
        int gm = m0 + wm * 64 + mt * 16 + quad * 4;
#pragma unroll
        for (int nt = 0; nt < 4; nt++) {
            int gn = n0 + wn * 64 + nt * 16 + l16;
            float bv = bias[gn];
#pragma unroll
            for (int r = 0; r < 4; r++)
                C[(size_t)(gm + r) * N + gn] = fmaxf(acc[mt][nt][r] + bv, 0.f);
        }
    }
}

// ---------------- dots + valid + near-threshold flagging ----------------
// block = one (b,l); thread t: n = t>>4 head, q = t&15 (float4 chunk of hd)
__global__ __launch_bounds__(256) void dots_kernel(const float* __restrict__ C,
                                                   const float* __restrict__ RH,
                                                   unsigned char* __restrict__ valid,
                                                   int* __restrict__ fcnt,
                                                   int* __restrict__ flist) {
    int bl = blockIdx.x;
    int t = threadIdx.x, n = t >> 4, q = t & 15;
    const float4 v = *(const float4*)&C[(size_t)bl * N_COLS + n * 64 + q * 4];
    const float4 w = *(const float4*)&RH[n * 64 + q * 4];
    float p = v.x * w.x + v.y * w.y + v.z * w.z + v.w * w.w;
#pragma unroll
    for (int s = 8; s >= 1; s >>= 1) p += __shfl_xor(p, s, 64);
    if (q == 0) {
        int b = bl >> 11, l = bl & (SEQ - 1);
        valid[((size_t)b * NH + n) * SEQ + l] = (p > 0.5f) ? 1 : 0;
        if (fabsf(p - 0.5f) < DELTA) {
            int idx = atomicAdd(fcnt, 1);
            if (idx < FLAG_CAP) flist[idx] = bl * NH + n;
        }
    }
}

// ---------------- exact fp64 refinement of flagged (b,l,n) ----------------
__global__ __launch_bounds__(64) void refine_kernel(const float* __restrict__ hs,
                                                    const float* __restrict__ BtK,
                                                    const float* __restrict__ K1b,
                                                    const float* __restrict__ RH,
                                                    const int* __restrict__ fcnt,
                                                    const int* __restrict__ flist,
                                                    unsigned char* __restrict__ valid) {
    int cnt = *fcnt;
    if (cnt > FLAG_CAP) cnt = FLAG_CAP;
    int d = threadIdx.x;   // 0..63
    for (int i = blockIdx.x; i < cnt; i += gridDim.x) {
        int code = flist[i];
        int n = code & (NH - 1);
        int bl = code >> 4;
        const float* x = hs + (size_t)bl * HDIM;
        const float* wp = BtK + (size_t)(n * 64 + d) * HDIM;
        double acc = (double)K1b[n * 64 + d];
        for (int k = 0; k < HDIM; k++) acc += (double)x[k] * (double)wp[k];
        double r = acc > 0.0 ? acc : 0.0;
        double contrib = r * (double)RH[n * 64 + d];
#pragma unroll
        for (int s = 32; s >= 1; s >>= 1) contrib += __shfl_xor(contrib, s, 64);
        if (d == 0) {
            int b = bl >> 11, l = bl & (SEQ - 1);
            valid[((size_t)b * NH + n) * SEQ + l] = (contrib > 0.5) ? 1 : 0;
        }
    }
}

// ---------------- nearest-valid scans ----------------
// one block (64 threads) per (b,n). Lane i owns positions [32i, 32i+32).
// forward: a=b=0; for j asc: if valid[j] {b=a; a=j}; fa[j]=a, fb[j]=b
//   (valid[0] with value 0 is a no-op vs init -> matches ref's mask_t[1:])
// backward: a=b=L-1; for j desc over [0,L-2]: if valid[j] {b=a; a=L-1-j}; ba[j]=a
//   (ref stores the MIRRORED index L-1-j; valid[L-1] excluded)
__global__ __launch_bounds__(64) void scan_kernel(const unsigned char* __restrict__ valid,
                                                  ushort4* __restrict__ maps) {
    int bn = blockIdx.x;                 // b*NH + n
    int b = bn >> 4, n = bn & (NH - 1);
    int lane = threadIdx.x;
    __shared__ unsigned int summ[64];

    const unsigned char* vp = valid + (size_t)bn * SEQ + lane * 32;
    uint4 c0 = *(const uint4*)vp;
    uint4 c1 = *(const uint4*)(vp + 16);
    unsigned int wds[8] = {c0.x, c0.y, c0.z, c0.w, c1.x, c1.y, c1.z, c1.w};
    unsigned int mask = 0;
#pragma unroll
    for (int i = 0; i < 8; i++) {
#pragma unroll
        for (int j = 0; j < 4; j++)
            mask |= (((wds[i] >> (8 * j)) & 0xffu) ? 1u : 0u) << (i * 4 + j);
    }

    // ---- forward ----
    int cnt = 0, va = 0, vb = 0;
#pragma unroll
    for (int tt = 0; tt < 32; tt++) {
        if (mask & (1u << tt)) { vb = va; va = lane * 32 + tt; cnt++; }
    }
    summ[lane] = (unsigned)((cnt > 2 ? 2 : cnt) | (va << 2) | (vb << 13));
    __syncthreads();
    int a = 0, bb_ = 0;
    for (int tt = 0; tt < lane; tt++) {
        unsigned s = summ[tt];
        int c = s & 3, sva = (s >> 2) & 2047, svb = (s >> 13) & 2047;
        if (c >= 2) { a = sva; bb_ = svb; }
        else if (c == 1) { bb_ = a; a = sva; }
    }
    unsigned int fres[32];
#pragma unroll
    for (int tt = 0; tt < 32; tt++) {
        if (mask & (1u << tt)) { bb_ = a; a = lane * 32 + tt; }
        fres[tt] = (unsigned)a | ((unsigned)bb_ << 16);
    }
    __syncthreads();

    // ---- backward (mirrored values) ----
    unsigned int maskb = mask;
    if (lane == 63) maskb &= ~(1u << 31);   // exclude j = L-1
    cnt = 0; va = 0; vb = 0;
#pragma unroll
    for (int tt = 31; tt >= 0; tt--) {
        if (maskb & (1u << tt)) { vb = va; va = (SEQ - 1) - (lane * 32 + tt); cnt++; }
    }
    summ[lane] = (unsigned)((cnt > 2 ? 2 : cnt) | (va << 2) | (vb << 13));
    __syncthreads();
    int a2 = SEQ - 1, b2 = SEQ - 1;
    for (int tt = 63; tt > lane; tt--) {
        unsigned s = summ[tt];
        int c = s & 3, sva = (s >> 2) & 2047, svb = (s >> 13) & 2047;
        if (c >= 2) { a2 = sva; b2 = svb; }
        else if (c == 1) { b2 = a2; a2 = sva; }
    }
#pragma unroll
    for (int tt = 31; tt >= 0; tt--) {
        int j = lane * 32 + tt;
        if (maskb & (1u << tt)) { b2 = a2; a2 = (SEQ - 1) - j; }
        unsigned f = fres[tt];
        maps[((size_t)b * SEQ + j) * NH + n] =
            make_ushort4((unsigned short)(f & 0xffffu), (unsigned short)(f >> 16),
                         (unsigned short)a2, (unsigned short)b2);
    }
}

// ---------------- gather + weighted sum ----------------
__global__ __launch_bounds__(256) void gather_kernel(const float* __restrict__ C,
                                                     const ushort4* __restrict__ maps,
                                                     const float* __restrict__ bw,
                                                     float* __restrict__ out) {
    int bl = blockIdx.x;
    int t = threadIdx.x, n = t >> 4, q = t & 15;
    int b = bl >> 11;
    ushort4 m = maps[(size_t)bl * NH + n];
    const float4 w = *(const float4*)&bw[n * 4];
    size_t colbase = (size_t)HDIM + n * 64 + q * 4;  // V1 half of C
    size_t rowb = (size_t)b * SEQ;
    const float4 v0 = *(const float4*)&C[(rowb + m.x) * N_COLS + colbase];
    const float4 v1 = *(const float4*)&C[(rowb + m.y) * N_COLS + colbase];
    const float4 v2 = *(const float4*)&C[(rowb + m.z) * N_COLS + colbase];
    const float4 v3 = *(const float4*)&C[(rowb + m.w) * N_COLS + colbase];
    float4 o;
    o.x = w.x * v0.x + w.y * v1.x + w.z * v2.x + w.w * v3.x;
    o.y = w.x * v0.y + w.y * v1.y + w.z * v2.y + w.w * v3.y;
    o.z = w.x * v0.z + w.y * v1.z + w.z * v2.z + w.w * v3.z;
    o.w = w.x * v0.w + w.y * v1.w + w.z * v2.w + w.w * v3.w;
    *(float4*)&out[(size_t)bl * (NH * HD) + n * 64 + q * 4] = o;
}

// ---------------- launch ----------------
extern "C" void kernel_launch(void* const* d_in, const int* in_sizes, int n_in,
                              void* d_out, int out_size, void* d_ws, size_t ws_size,
                              hipStream_t stream) {
    (void)in_sizes; (void)n_in; (void)out_size; (void)ws_size;
    const float* hs  = (const float*)d_in[0];
    const float* K1w = (const float*)d_in[1];
    const float* K1b = (const float*)d_in[2];
    const float* V1w = (const float*)d_in[3];
    const float* V1b = (const float*)d_in[4];
    const float* bw  = (const float*)d_in[5];
    const float* RH  = (const float*)d_in[6];
    float* out = (float*)d_out;
    char* ws = (char*)d_ws;

    unsigned short* Abf  = (unsigned short*)(ws + OFF_A);
    unsigned short* Btbf = (unsigned short*)(ws + OFF_BT);
    float* BtK   = (float*)(ws + OFF_BTK);
    float* bias  = (float*)(ws + OFF_BIAS);
    float* C     = (float*)(ws + OFF_C);
    unsigned char* valid = (unsigned char*)(ws + OFF_VALID);
    ushort4* maps = (ushort4*)(ws + OFF_MAPS);
    int* fcnt = (int*)(ws + OFF_FCNT);
    int* flist = (int*)(ws + OFF_FLIST);

    zero_cnt_kernel<<<1, 1, 0, stream>>>(fcnt);
    cvt_hs_kernel<<<16384, 256, 0, stream>>>((const float4*)hs, (ushort4*)Abf);
    cvt_w_kernel<<<dim3(32, 32, 2), 256, 0, stream>>>(K1w, V1w, Btbf, BtK);
    cvt_bias_kernel<<<8, 256, 0, stream>>>(K1b, V1b, bias);
    gemm_kernel<<<dim3(N_COLS / 128, M_ROWS / 128), 256, 0, stream>>>(Abf, Btbf, bias, C);
    dots_kernel<<<BS * SEQ, 256, 0, stream>>>(C, RH, valid, fcnt, flist);
    refine_kernel<<<2048, 64, 0, stream>>>(hs, BtK, K1b, RH, fcnt, flist, valid);
    scan_kernel<<<BS * NH, 64, 0, stream>>>(valid, maps);
    gather_kernel<<<BS * SEQ, 256, 0, stream>>>(C, maps, bw, out);
}

// Round 2
// 479.846 us; speedup vs baseline: 1.0173x; 1.0173x over previous
//
#include <hip/hip_runtime.h>
#include <hip/hip_bf16.h>
#include <cstdint>

// ---------------- problem dims ----------------
#define BS 8
#define SEQ 2048
#define HDIM 1024
#define NH 16
#define HD 64
#define M_ROWS (BS * SEQ)   // 16384
#define N_COLS (2 * HDIM)   // 2048  (cols 0..1023 = K1, 1024..2047 = V1)
#define KDIM HDIM           // 1024

#define DELTA 0.025f
#define FLAG_CAP 32768

// ---------------- workspace layout (bytes) ----------------
#define OFF_A      ((size_t)0)           // bf16 A [M,K]            33,554,432
#define OFF_BT     ((size_t)33554432)    // bf16 Bt [N,K]            4,194,304
#define OFF_BIAS   ((size_t)41943040)    // f32 [2048]                   8,192
#define OFF_C      ((size_t)41951232)    // f32 C [M,N]            134,217,728
#define OFF_VALID  ((size_t)176168960)   // u8 [BS][NH][SEQ]           262,144
#define OFF_MAPS   ((size_t)176431104)   // ushort4 [BS][SEQ][NH]    2,097,152
#define OFF_FCNT   ((size_t)178528256)   // int
#define OFF_FLIST  ((size_t)178528512)   // int[FLAG_CAP]

typedef __attribute__((ext_vector_type(8))) __bf16 bf16x8;
typedef __attribute__((ext_vector_type(4))) float f32x4;

// float -> bf16 bits, round-to-nearest-even (inputs are finite)
__device__ __forceinline__ unsigned short f2bf(float f) {
    unsigned int x = __builtin_bit_cast(unsigned int, f);
    unsigned int r = x + 0x7fffu + ((x >> 16) & 1u);
    return (unsigned short)(r >> 16);
}

// async 16B global -> LDS (dest = wave-uniform LDS base + lane*16)
__device__ __forceinline__ void g2l16(const void* gp, void* lp) {
    __builtin_amdgcn_global_load_lds(
        (__attribute__((address_space(1))) void*)(void*)gp,
        (__attribute__((address_space(3))) void*)lp, 16, 0, 0);
}

// ---------------- prep kernels ----------------
__global__ __launch_bounds__(256) void cvt_hs_kernel(const float4* __restrict__ in,
                                                     ushort4* __restrict__ outp) {
    int i = blockIdx.x * 256 + threadIdx.x;   // 4,194,304 total
    float4 v = in[i];
    ushort4 o;
    o.x = f2bf(v.x); o.y = f2bf(v.y); o.z = f2bf(v.z); o.w = f2bf(v.w);
    outp[i] = o;
}

// transpose W [K=1024][N=1024] -> Bt[n][k] (bf16)
__global__ __launch_bounds__(256) void cvt_w_kernel(const float* __restrict__ K1w,
                                                    const float* __restrict__ V1w,
                                                    unsigned short* __restrict__ Bt) {
    __shared__ float tile[32][33];
    const float* W = blockIdx.z ? V1w : K1w;
    int tn = blockIdx.x, tk = blockIdx.y;
    int t = threadIdx.x;
    int r = t >> 3;            // 0..31
    int c4 = (t & 7) * 4;      // 0,4,..,28
    const float4 v = *(const float4*)&W[(size_t)(tk * 32 + r) * 1024 + tn * 32 + c4];
    tile[r][c4 + 0] = v.x; tile[r][c4 + 1] = v.y; tile[r][c4 + 2] = v.z; tile[r][c4 + 3] = v.w;
    __syncthreads();
    int n = tn * 32 + r;
    int k = tk * 32 + c4;
    float f0 = tile[c4 + 0][r], f1 = tile[c4 + 1][r], f2 = tile[c4 + 2][r], f3 = tile[c4 + 3][r];
    size_t obase = ((size_t)blockIdx.z * 1024 + n) * 1024 + k;
    ushort4 o; o.x = f2bf(f0); o.y = f2bf(f1); o.z = f2bf(f2); o.w = f2bf(f3);
    *(ushort4*)&Bt[obase] = o;
}

__global__ void cvt_bias_kernel(const float* __restrict__ K1b, const float* __restrict__ V1b,
                                float* __restrict__ bias, int* __restrict__ fcnt) {
    int i = blockIdx.x * 256 + threadIdx.x;   // 2048 total
    bias[i] = (i < 1024) ? K1b[i] : V1b[i - 1024];
    if (i == 0) *fcnt = 0;
}

// ---------------- GEMM (m97 pattern): C = relu(A @ Bt^T + bias) ----------------
// A [M,K] bf16, Bt [N,K] bf16, C [M,N] f32. 128x128 tile, BK=32, 4 waves 2x2.
__global__ __launch_bounds__(256) void gemm_kernel(const unsigned short* __restrict__ Abf,
                                                   const unsigned short* __restrict__ Btbf,
                                                   const float* __restrict__ bias,
                                                   float* __restrict__ C) {
    constexpr int K = KDIM, N = N_COLS, BK = 32;
    __shared__ unsigned short As[128 * BK];   // row-major [128][32]
    __shared__ unsigned short Bs[128 * BK];
    const int t = threadIdx.x;
    const int wave = t >> 6, lane = t & 63;
    const int wm = wave >> 1, wn = wave & 1;
    const int l16 = lane & 15, quad = lane >> 4;
    const int m0 = blockIdx.y * 128, n0 = blockIdx.x * 128;

    f32x4 zero4 = {0.f, 0.f, 0.f, 0.f};
    f32x4 acc[4][4];
#pragma unroll
    for (int i = 0; i < 4; i++)
#pragma unroll
        for (int j = 0; j < 4; j++) acc[i][j] = zero4;

    const int srow = t >> 2;          // 0..63
    const int sk = (t & 3) * 8;       // k element offset of this lane's 16B
    const unsigned short* gA = Abf + (size_t)(m0 + srow) * K + sk;
    const unsigned short* gB = Btbf + (size_t)(n0 + srow) * K + sk;
    char* lAs = (char*)As + (size_t)wave * 1024;
    char* lBs = (char*)Bs + (size_t)wave * 1024;

    for (int k0 = 0; k0 < K; k0 += BK) {
        g2l16(gA + k0, lAs);
        g2l16(gA + (size_t)64 * K + k0, lAs + 4096);
        g2l16(gB + k0, lBs);
        g2l16(gB + (size_t)64 * K + k0, lBs + 4096);
        __syncthreads();   // drains global_load_lds (vmcnt) + barrier
        bf16x8 af[4], bfr[4];
#pragma unroll
        for (int mt = 0; mt < 4; mt++)
            af[mt] = *(const bf16x8*)&As[(wm * 64 + mt * 16 + l16) * BK + quad * 8];
#pragma unroll
        for (int nt = 0; nt < 4; nt++)
            bfr[nt] = *(const bf16x8*)&Bs[(wn * 64 + nt * 16 + l16) * BK + quad * 8];
#pragma unroll
        for (int mt = 0; mt < 4; mt++)
#pragma unroll
            for (int nt = 0; nt < 4; nt++)
                acc[mt][nt] = __builtin_amdgcn_mfma_f32_16x16x32_bf16(af[mt], bfr[nt], acc[mt][nt], 0, 0, 0);
        __syncthreads();
    }
    // epilogue: bias + relu, f32 store. C/D: row=quad*4+reg, col=l16
#pragma unroll
    for (int mt = 0; mt < 4; mt++) {
        int gm = m0 + wm * 64 + mt * 16 + quad * 4;
#pragma unroll
        for (int nt = 0; nt < 4; nt++) {
            int gn = n0 + wn * 64 + nt * 16 + l16;
            float bv = bias[gn];
#pragma unroll
            for (int r = 0; r < 4; r++)
                C[(size_t)(gm + r) * N + gn] = fmaxf(acc[mt][nt][r] + bv, 0.f);
        }
    }
}

// ---------------- dots + valid + near-threshold flagging ----------------
// block = one (b,l); thread t: n = t>>4 head, q = t&15 (float4 chunk of hd)
__global__ __launch_bounds__(256) void dots_kernel(const float* __restrict__ C,
                                                   const float* __restrict__ RH,
                                                   unsigned char* __restrict__ valid,
                                                   int* __restrict__ fcnt,
                                                   int* __restrict__ flist) {
    int bl = blockIdx.x;
    int t = threadIdx.x, n = t >> 4, q = t & 15;
    const float4 v = *(const float4*)&C[(size_t)bl * N_COLS + n * 64 + q * 4];
    const float4 w = *(const float4*)&RH[n * 64 + q * 4];
    float p = v.x * w.x + v.y * w.y + v.z * w.z + v.w * w.w;
#pragma unroll
    for (int s = 8; s >= 1; s >>= 1) p += __shfl_xor(p, s, 64);
    if (q == 0) {
        int b = bl >> 11, l = bl & (SEQ - 1);
        valid[((size_t)b * NH + n) * SEQ + l] = (p > 0.5f) ? 1 : 0;
        if (fabsf(p - 0.5f) < DELTA) {
            int idx = atomicAdd(fcnt, 1);
            if (idx < FLAG_CAP) flist[idx] = bl * NH + n;
        }
    }
}

// ---------------- exact fp64 refinement of flagged (b,l,n) ----------------
// Lane d owns head-dim d. Weights read straight from K1_w's NATIVE layout
// [k][n*64+d]: lanes 0..63 hit consecutive f32s -> one 256B transaction per k.
// x[k] is wave-uniform -> scalar load. k unrolled x4 to break fp64 FMA chain.
__global__ __launch_bounds__(64) void refine_kernel(const float* __restrict__ hs,
                                                    const float* __restrict__ K1w,
                                                    const float* __restrict__ K1b,
                                                    const float* __restrict__ RH,
                                                    const int* __restrict__ fcnt,
                                                    const int* __restrict__ flist,
                                                    unsigned char* __restrict__ valid) {
    int cnt = *fcnt;
    if (cnt > FLAG_CAP) cnt = FLAG_CAP;
    int d = threadIdx.x;   // 0..63
    for (int i = blockIdx.x; i < cnt; i += gridDim.x) {
        int code = flist[i];
        int n = code & (NH - 1);
        int bl = code >> 4;
        const float* x = hs + (size_t)bl * HDIM;
        const float* wp = K1w + n * 64 + d;       // row stride 1024 over k
        double a0 = 0.0, a1 = 0.0, a2 = 0.0, a3 = 0.0;
        for (int k = 0; k < HDIM; k += 4) {
            a0 += (double)x[k + 0] * (double)wp[(size_t)(k + 0) * 1024];
            a1 += (double)x[k + 1] * (double)wp[(size_t)(k + 1) * 1024];
            a2 += (double)x[k + 2] * (double)wp[(size_t)(k + 2) * 1024];
            a3 += (double)x[k + 3] * (double)wp[(size_t)(k + 3) * 1024];
        }
        double acc = ((a0 + a1) + (a2 + a3)) + (double)K1b[n * 64 + d];
        double r = acc > 0.0 ? acc : 0.0;
        double contrib = r * (double)RH[n * 64 + d];
#pragma unroll
        for (int s = 32; s >= 1; s >>= 1) contrib += __shfl_xor(contrib, s, 64);
        if (d == 0) {
            int b = bl >> 11, l = bl & (SEQ - 1);
            valid[((size_t)b * NH + n) * SEQ + l] = (contrib > 0.5) ? 1 : 0;
        }
    }
}

// ---------------- nearest-valid scans ----------------
// one block (64 threads) per (b,n). Lane i owns positions [32i, 32i+32).
// forward: a=b=0; for j asc: if valid[j] {b=a; a=j}; fa[j]=a, fb[j]=b
//   (valid[0] with value 0 is a no-op vs init -> matches ref's mask_t[1:])
// backward: a=b=L-1; for j desc over [0,L-2]: if valid[j] {b=a; a=L-1-j}; ba[j]=a
//   (ref stores the MIRRORED index L-1-j; valid[L-1] excluded)
__global__ __launch_bounds__(64) void scan_kernel(const unsigned char* __restrict__ valid,
                                                  ushort4* __restrict__ maps) {
    int bn = blockIdx.x;                 // b*NH + n
    int b = bn >> 4, n = bn & (NH - 1);
    int lane = threadIdx.x;
    __shared__ unsigned int summ[64];

    const unsigned char* vp = valid + (size_t)bn * SEQ + lane * 32;
    uint4 c0 = *(const uint4*)vp;
    uint4 c1 = *(const uint4*)(vp + 16);
    unsigned int wds[8] = {c0.x, c0.y, c0.z, c0.w, c1.x, c1.y, c1.z, c1.w};
    unsigned int mask = 0;
#pragma unroll
    for (int i = 0; i < 8; i++) {
#pragma unroll
        for (int j = 0; j < 4; j++)
            mask |= (((wds[i] >> (8 * j)) & 0xffu) ? 1u : 0u) << (i * 4 + j);
    }

    // ---- forward ----
    int cnt = 0, va = 0, vb = 0;
#pragma unroll
    for (int tt = 0; tt < 32; tt++) {
        if (mask & (1u << tt)) { vb = va; va = lane * 32 + tt; cnt++; }
    }
    summ[lane] = (unsigned)((cnt > 2 ? 2 : cnt) | (va << 2) | (vb << 13));
    __syncthreads();
    int a = 0, bb_ = 0;
    for (int tt = 0; tt < lane; tt++) {
        unsigned s = summ[tt];
        int c = s & 3, sva = (s >> 2) & 2047, svb = (s >> 13) & 2047;
        if (c >= 2) { a = sva; bb_ = svb; }
        else if (c == 1) { bb_ = a; a = sva; }
    }
    unsigned int fres[32];
#pragma unroll
    for (int tt = 0; tt < 32; tt++) {
        if (mask & (1u << tt)) { bb_ = a; a = lane * 32 + tt; }
        fres[tt] = (unsigned)a | ((unsigned)bb_ << 16);
    }
    __syncthreads();

    // ---- backward (mirrored values) ----
    unsigned int maskb = mask;
    if (lane == 63) maskb &= ~(1u << 31);   // exclude j = L-1
    cnt = 0; va = 0; vb = 0;
#pragma unroll
    for (int tt = 31; tt >= 0; tt--) {
        if (maskb & (1u << tt)) { vb = va; va = (SEQ - 1) - (lane * 32 + tt); cnt++; }
    }
    summ[lane] = (unsigned)((cnt > 2 ? 2 : cnt) | (va << 2) | (vb << 13));
    __syncthreads();
    int a2 = SEQ - 1, b2 = SEQ - 1;
    for (int tt = 63; tt > lane; tt--) {
        unsigned s = summ[tt];
        int c = s & 3, sva = (s >> 2) & 2047, svb = (s >> 13) & 2047;
        if (c >= 2) { a2 = sva; b2 = svb; }
        else if (c == 1) { b2 = a2; a2 = sva; }
    }
#pragma unroll
    for (int tt = 31; tt >= 0; tt--) {
        int j = lane * 32 + tt;
        if (maskb & (1u << tt)) { b2 = a2; a2 = (SEQ - 1) - j; }
        unsigned f = fres[tt];
        maps[((size_t)b * SEQ + j) * NH + n] =
            make_ushort4((unsigned short)(f & 0xffffu), (unsigned short)(f >> 16),
                         (unsigned short)a2, (unsigned short)b2);
    }
}

// ---------------- gather + weighted sum ----------------
__global__ __launch_bounds__(256) void gather_kernel(const float* __restrict__ C,
                                                     const ushort4* __restrict__ maps,
                                                     const float* __restrict__ bw,
                                                     float* __restrict__ out) {
    int bl = blockIdx.x;
    int t = threadIdx.x, n = t >> 4, q = t & 15;
    int b = bl >> 11;
    ushort4 m = maps[(size_t)bl * NH + n];
    const float4 w = *(const float4*)&bw[n * 4];
    size_t colbase = (size_t)HDIM + n * 64 + q * 4;  // V1 half of C
    size_t rowb = (size_t)b * SEQ;
    const float4 v0 = *(const float4*)&C[(rowb + m.x) * N_COLS + colbase];
    const float4 v1 = *(const float4*)&C[(rowb + m.y) * N_COLS + colbase];
    const float4 v2 = *(const float4*)&C[(rowb + m.z) * N_COLS + colbase];
    const float4 v3 = *(const float4*)&C[(rowb + m.w) * N_COLS + colbase];
    float4 o;
    o.x = w.x * v0.x + w.y * v1.x + w.z * v2.x + w.w * v3.x;
    o.y = w.x * v0.y + w.y * v1.y + w.z * v2.y + w.w * v3.y;
    o.z = w.x * v0.z + w.y * v1.z + w.z * v2.z + w.w * v3.z;
    o.w = w.x * v0.w + w.y * v1.w + w.z * v2.w + w.w * v3.w;
    *(float4*)&out[(size_t)bl * (NH * HD) + n * 64 + q * 4] = o;
}

// ---------------- launch ----------------
extern "C" void kernel_launch(void* const* d_in, const int* in_sizes, int n_in,
                              void* d_out, int out_size, void* d_ws, size_t ws_size,
                              hipStream_t stream) {
    (void)in_sizes; (void)n_in; (void)out_size; (void)ws_size;
    const float* hs  = (const float*)d_in[0];
    const float* K1w = (const float*)d_in[1];
    const float* K1b = (const float*)d_in[2];
    const float* V1w = (const float*)d_in[3];
    const float* V1b = (const float*)d_in[4];
    const float* bw  = (const float*)d_in[5];
    const float* RH  = (const float*)d_in[6];
    float* out = (float*)d_out;
    char* ws = (char*)d_ws;

    unsigned short* Abf  = (unsigned short*)(ws + OFF_A);
    unsigned short* Btbf = (unsigned short*)(ws + OFF_BT);
    float* bias  = (float*)(ws + OFF_BIAS);
    float* C     = (float*)(ws + OFF_C);
    unsigned char* valid = (unsigned char*)(ws + OFF_VALID);
    ushort4* maps = (ushort4*)(ws + OFF_MAPS);
    int* fcnt = (int*)(ws + OFF_FCNT);
    int* flist = (int*)(ws + OFF_FLIST);

    cvt_bias_kernel<<<8, 256, 0, stream>>>(K1b, V1b, bias, fcnt);
    cvt_hs_kernel<<<16384, 256, 0, stream>>>((const float4*)hs, (ushort4*)Abf);
    cvt_w_kernel<<<dim3(32, 32, 2), 256, 0, stream>>>(K1w, V1w, Btbf);
    gemm_kernel<<<dim3(N_COLS / 128, M_ROWS / 128), 256, 0, stream>>>(Abf, Btbf, bias, C);
    dots_kernel<<<BS * SEQ, 256, 0, stream>>>(C, RH, valid, fcnt, flist);
    refine_kernel<<<2048, 64, 0, stream>>>(hs, K1w, K1b, RH, fcnt, flist, valid);
    scan_kernel<<<BS * NH, 64, 0, stream>>>(valid, maps);
    gather_kernel<<<BS * SEQ, 256, 0, stream>>>(C, maps, bw, out);
}

// Round 3
// 453.367 us; speedup vs baseline: 1.0768x; 1.0584x over previous
//
#include <hip/hip_runtime.h>
#include <hip/hip_bf16.h>
#include <cstdint>

// ---------------- problem dims ----------------
#define BS 8
#define SEQ 2048
#define HDIM 1024
#define NH 16
#define HD 64
#define M_ROWS (BS * SEQ)   // 16384
#define N_COLS (2 * HDIM)   // 2048 GEMM cols: 0..1023 = K1 (dots only), 1024..2047 = V1
#define KDIM HDIM           // 1024

#define DELTA 0.025f
#define PER_HEAD_CAP 8192        // flagged (b,l) per head; expected ~310, cap >> tail
#define TASKS_PER_BLOCK 16
#define GROUPS_PER_HEAD (PER_HEAD_CAP / TASKS_PER_BLOCK)   // 512

// ---------------- workspace layout (bytes) ----------------
#define OFF_A      ((size_t)0)           // bf16 A [M,K]             33,554,432
#define OFF_BT     ((size_t)33554432)    // bf16 Bt [N,K]             4,194,304
#define OFF_FCNT   ((size_t)37748736)    // int[16]
#define OFF_FLIST  ((size_t)37748800)    // int[16][8192]               524,288
#define OFF_BIAS   ((size_t)38273088)    // f32 [2048]
#define OFF_CV     ((size_t)41943040)    // f32 CV [M,1024] (V1 only) 67,108,864
#define OFF_VALID  ((size_t)109051904)   // u8 [BS][NH][SEQ]             262,144
#define OFF_MAPS   ((size_t)109314048)   // ushort4 [BS][SEQ][NH]      2,097,152
// total ~111.4 MB

typedef __attribute__((ext_vector_type(8))) __bf16 bf16x8;
typedef __attribute__((ext_vector_type(4))) float f32x4;

// float -> bf16 bits, round-to-nearest-even (inputs are finite)
__device__ __forceinline__ unsigned short f2bf(float f) {
    unsigned int x = __builtin_bit_cast(unsigned int, f);
    unsigned int r = x + 0x7fffu + ((x >> 16) & 1u);
    return (unsigned short)(r >> 16);
}

// async 16B global -> LDS (dest = wave-uniform LDS base + lane*16)
__device__ __forceinline__ void g2l16(const void* gp, void* lp) {
    __builtin_amdgcn_global_load_lds(
        (__attribute__((address_space(1))) void*)(void*)gp,
        (__attribute__((address_space(3))) void*)lp, 16, 0, 0);
}

// ---------------- prep kernels ----------------
__global__ __launch_bounds__(256) void cvt_hs_kernel(const float4* __restrict__ in,
                                                     ushort4* __restrict__ outp) {
    int i = blockIdx.x * 256 + threadIdx.x;   // 4,194,304 total
    float4 v = in[i];
    ushort4 o;
    o.x = f2bf(v.x); o.y = f2bf(v.y); o.z = f2bf(v.z); o.w = f2bf(v.w);
    outp[i] = o;
}

// transpose W [K=1024][N=1024] -> Bt[n][k] (bf16)
__global__ __launch_bounds__(256) void cvt_w_kernel(const float* __restrict__ K1w,
                                                    const float* __restrict__ V1w,
                                                    unsigned short* __restrict__ Bt) {
    __shared__ float tile[32][33];
    const float* W = blockIdx.z ? V1w : K1w;
    int tn = blockIdx.x, tk = blockIdx.y;
    int t = threadIdx.x;
    int r = t >> 3;            // 0..31
    int c4 = (t & 7) * 4;      // 0,4,..,28
    const float4 v = *(const float4*)&W[(size_t)(tk * 32 + r) * 1024 + tn * 32 + c4];
    tile[r][c4 + 0] = v.x; tile[r][c4 + 1] = v.y; tile[r][c4 + 2] = v.z; tile[r][c4 + 3] = v.w;
    __syncthreads();
    int n = tn * 32 + r;
    int k = tk * 32 + c4;
    float f0 = tile[c4 + 0][r], f1 = tile[c4 + 1][r], f2 = tile[c4 + 2][r], f3 = tile[c4 + 3][r];
    size_t obase = ((size_t)blockIdx.z * 1024 + n) * 1024 + k;
    ushort4 o; o.x = f2bf(f0); o.y = f2bf(f1); o.z = f2bf(f2); o.w = f2bf(f3);
    *(ushort4*)&Bt[obase] = o;
}

__global__ void cvt_bias_kernel(const float* __restrict__ K1b, const float* __restrict__ V1b,
                                float* __restrict__ bias, int* __restrict__ fcnt) {
    int i = blockIdx.x * 256 + threadIdx.x;   // 2048 total
    bias[i] = (i < 1024) ? K1b[i] : V1b[i - 1024];
    if (i < 16) fcnt[i] = 0;
}

// ---------------- GEMM + fused dots ----------------
// A [M,K] bf16, Bt [N,K] bf16. 128x128 tile, BK=32, 4 waves 2x2.
// Blocks with n0 <  1024: each wave's 64x64 block == one head's K1 slab ->
//   compute dots = sum_d relu(acc+bias)*RH in-register, write valid + flag list.
//   K-half of C is NEVER stored.
// Blocks with n0 >= 1024: store relu(acc+bias) into CV [M][1024].
__global__ __launch_bounds__(256) void gemm_kernel(const unsigned short* __restrict__ Abf,
                                                   const unsigned short* __restrict__ Btbf,
                                                   const float* __restrict__ bias,
                                                   const float* __restrict__ RH,
                                                   float* __restrict__ CV,
                                                   unsigned char* __restrict__ valid,
                                                   int* __restrict__ fcnt,
                                                   int* __restrict__ flist) {
    constexpr int K = KDIM, BK = 32;
    __shared__ unsigned short As[128 * BK];   // row-major [128][32]
    __shared__ unsigned short Bs[128 * BK];
    const int t = threadIdx.x;
    const int wave = t >> 6, lane = t & 63;
    const int wm = wave >> 1, wn = wave & 1;
    const int l16 = lane & 15, quad = lane >> 4;
    const int m0 = blockIdx.y * 128, n0 = blockIdx.x * 128;

    f32x4 zero4 = {0.f, 0.f, 0.f, 0.f};
    f32x4 acc[4][4];
#pragma unroll
    for (int i = 0; i < 4; i++)
#pragma unroll
        for (int j = 0; j < 4; j++) acc[i][j] = zero4;

    const int srow = t >> 2;          // 0..63
    const int sk = (t & 3) * 8;       // k element offset of this lane's 16B
    const unsigned short* gA = Abf + (size_t)(m0 + srow) * K + sk;
    const unsigned short* gB = Btbf + (size_t)(n0 + srow) * K + sk;
    char* lAs = (char*)As + (size_t)wave * 1024;
    char* lBs = (char*)Bs + (size_t)wave * 1024;

    for (int k0 = 0; k0 < K; k0 += BK) {
        g2l16(gA + k0, lAs);
        g2l16(gA + (size_t)64 * K + k0, lAs + 4096);
        g2l16(gB + k0, lBs);
        g2l16(gB + (size_t)64 * K + k0, lBs + 4096);
        __syncthreads();   // drains global_load_lds (vmcnt) + barrier
        bf16x8 af[4], bfr[4];
#pragma unroll
        for (int mt = 0; mt < 4; mt++)
            af[mt] = *(const bf16x8*)&As[(wm * 64 + mt * 16 + l16) * BK + quad * 8];
#pragma unroll
        for (int nt = 0; nt < 4; nt++)
            bfr[nt] = *(const bf16x8*)&Bs[(wn * 64 + nt * 16 + l16) * BK + quad * 8];
#pragma unroll
        for (int mt = 0; mt < 4; mt++)
#pragma unroll
            for (int nt = 0; nt < 4; nt++)
                acc[mt][nt] = __builtin_amdgcn_mfma_f32_16x16x32_bf16(af[mt], bfr[nt], acc[mt][nt], 0, 0, 0);
        __syncthreads();
    }
    // C/D fragment: row = quad*4 + reg, col = l16 (within each 16x16 tile)
    if (n0 < HDIM) {
        // ---- fused dots: this wave's head ----
        const int n = (n0 >> 6) + wn;
        float rh[4], bv[4];
#pragma unroll
        for (int nt = 0; nt < 4; nt++) {
            int col = n * 64 + nt * 16 + l16;
            rh[nt] = RH[col];
            bv[nt] = bias[col];
        }
#pragma unroll
        for (int mt = 0; mt < 4; mt++) {
#pragma unroll
            for (int r = 0; r < 4; r++) {
                float p = 0.f;
#pragma unroll
                for (int nt = 0; nt < 4; nt++)
                    p += fmaxf(acc[mt][nt][r] + bv[nt], 0.f) * rh[nt];
#pragma unroll
                for (int s = 8; s >= 1; s >>= 1) p += __shfl_xor(p, s, 64);
                if (l16 == 0) {
                    int row = m0 + wm * 64 + mt * 16 + quad * 4 + r;   // b*SEQ + l
                    int b = row >> 11, l = row & (SEQ - 1);
                    valid[((size_t)b * NH + n) * SEQ + l] = (p > 0.5f) ? 1 : 0;
                    if (fabsf(p - 0.5f) < DELTA) {
                        int idx = atomicAdd(&fcnt[n], 1);
                        if (idx < PER_HEAD_CAP) flist[n * PER_HEAD_CAP + idx] = row;
                    }
                }
            }
        }
    } else {
        // ---- V-half: bias + relu, store to CV ----
        const int nv0 = n0 - HDIM;
#pragma unroll
        for (int mt = 0; mt < 4; mt++) {
            int gm = m0 + wm * 64 + mt * 16 + quad * 4;
#pragma unroll
            for (int nt = 0; nt < 4; nt++) {
                int gn = nv0 + wn * 64 + nt * 16 + l16;
                float bvv = bias[HDIM + gn];
#pragma unroll
                for (int r = 0; r < 4; r++)
                    CV[(size_t)(gm + r) * HDIM + gn] = fmaxf(acc[mt][nt][r] + bvv, 0.f);
            }
        }
    }
}

// ---------------- exact fp64 refinement, head-bucketed ----------------
// Block = (head n, group g of 16 tasks sharing n). 256 threads.
// K1_w's 64-col slab for head n is tiled through LDS 64 rows at a time and
// applied to all 16 task x-vectors -> weight traffic /16, LDS-resident compute.
#define WSTRIDE 68
#define XSTRIDE 68
__global__ __launch_bounds__(256) void refine_kernel(const float* __restrict__ hs,
                                                     const float* __restrict__ K1w,
                                                     const float* __restrict__ K1b,
                                                     const float* __restrict__ RH,
                                                     const int* __restrict__ fcnt,
                                                     const int* __restrict__ flist,
                                                     unsigned char* __restrict__ valid) {
    const int n = blockIdx.x >> 9;          // GROUPS_PER_HEAD = 512
    const int g = blockIdx.x & (GROUPS_PER_HEAD - 1);
    int cnt = fcnt[n];
    if (cnt > PER_HEAD_CAP) cnt = PER_HEAD_CAP;
    const int base = g * TASKS_PER_BLOCK;
    if (base >= cnt) return;

    __shared__ float Wt[64 * WSTRIDE];
    __shared__ float Xt[16 * XSTRIDE];
    __shared__ int blArr[16];
    const int t = threadIdx.x;
    if (t < 16) {
        int bl = -1;
        if (base + t < cnt) bl = flist[n * PER_HEAD_CAP + base + t];
        blArr[t] = bl;
    }
    __syncthreads();
    const int xj = t >> 4, xe = (t & 15) * 4;   // X-load role
    const int bl_j = blArr[xj];
    const int wr = t >> 2, wc = (t & 3) * 16;   // W-load role
    const int jj = t >> 6, d = t & 63;          // compute role
    const float* wsrc0 = K1w + n * 64 + wc;

    double acc0 = 0.0, acc1 = 0.0, acc2 = 0.0, acc3 = 0.0;
    for (int kc = 0; kc < KDIM; kc += 64) {
        const float* wsrc = wsrc0 + (size_t)(kc + wr) * 1024;
        float4 w0 = *(const float4*)(wsrc);
        float4 w1 = *(const float4*)(wsrc + 4);
        float4 w2 = *(const float4*)(wsrc + 8);
        float4 w3 = *(const float4*)(wsrc + 12);
        float4 xv = {0.f, 0.f, 0.f, 0.f};
        if (bl_j >= 0) xv = *(const float4*)&hs[(size_t)bl_j * HDIM + kc + xe];
        __syncthreads();   // previous chunk's compute done before overwrite
        *(float4*)&Wt[wr * WSTRIDE + wc]      = w0;
        *(float4*)&Wt[wr * WSTRIDE + wc + 4]  = w1;
        *(float4*)&Wt[wr * WSTRIDE + wc + 8]  = w2;
        *(float4*)&Wt[wr * WSTRIDE + wc + 12] = w3;
        *(float4*)&Xt[xj * XSTRIDE + xe] = xv;
        __syncthreads();
#pragma unroll 8
        for (int k = 0; k < 64; k++) {
            double w = (double)Wt[k * WSTRIDE + d];
            acc0 += (double)Xt[(jj * 4 + 0) * XSTRIDE + k] * w;
            acc1 += (double)Xt[(jj * 4 + 1) * XSTRIDE + k] * w;
            acc2 += (double)Xt[(jj * 4 + 2) * XSTRIDE + k] * w;
            acc3 += (double)Xt[(jj * 4 + 3) * XSTRIDE + k] * w;
        }
    }
    const double bias_d = (double)K1b[n * 64 + d];
    const double rh_d = (double)RH[n * 64 + d];
    double accs[4] = {acc0, acc1, acc2, acc3};
#pragma unroll
    for (int u = 0; u < 4; u++) {
        double k1 = accs[u] + bias_d;
        if (k1 < 0.0) k1 = 0.0;
        double contrib = k1 * rh_d;
#pragma unroll
        for (int s = 32; s >= 1; s >>= 1) contrib += __shfl_xor(contrib, s, 64);
        int j = jj * 4 + u;
        int bl = blArr[j];
        if (d == 0 && bl >= 0) {
            int b = bl >> 11, l = bl & (SEQ - 1);
            valid[((size_t)b * NH + n) * SEQ + l] = (contrib > 0.5) ? 1 : 0;
        }
    }
}

// ---------------- nearest-valid scans ----------------
// one block (64 threads) per (b,n). Lane i owns positions [32i, 32i+32).
__global__ __launch_bounds__(64) void scan_kernel(const unsigned char* __restrict__ valid,
                                                  ushort4* __restrict__ maps) {
    int bn = blockIdx.x;                 // b*NH + n
    int b = bn >> 4, n = bn & (NH - 1);
    int lane = threadIdx.x;
    __shared__ unsigned int summ[64];

    const unsigned char* vp = valid + (size_t)bn * SEQ + lane * 32;
    uint4 c0 = *(const uint4*)vp;
    uint4 c1 = *(const uint4*)(vp + 16);
    unsigned int wds[8] = {c0.x, c0.y, c0.z, c0.w, c1.x, c1.y, c1.z, c1.w};
    unsigned int mask = 0;
#pragma unroll
    for (int i = 0; i < 8; i++) {
#pragma unroll
        for (int j = 0; j < 4; j++)
            mask |= (((wds[i] >> (8 * j)) & 0xffu) ? 1u : 0u) << (i * 4 + j);
    }

    // ---- forward ----
    int cnt = 0, va = 0, vb = 0;
#pragma unroll
    for (int tt = 0; tt < 32; tt++) {
        if (mask & (1u << tt)) { vb = va; va = lane * 32 + tt; cnt++; }
    }
    summ[lane] = (unsigned)((cnt > 2 ? 2 : cnt) | (va << 2) | (vb << 13));
    __syncthreads();
    int a = 0, bb_ = 0;
    for (int tt = 0; tt < lane; tt++) {
        unsigned s = summ[tt];
        int c = s & 3, sva = (s >> 2) & 2047, svb = (s >> 13) & 2047;
        if (c >= 2) { a = sva; bb_ = svb; }
        else if (c == 1) { bb_ = a; a = sva; }
    }
    unsigned int fres[32];
#pragma unroll
    for (int tt = 0; tt < 32; tt++) {
        if (mask & (1u << tt)) { bb_ = a; a = lane * 32 + tt; }
        fres[tt] = (unsigned)a | ((unsigned)bb_ << 16);
    }
    __syncthreads();

    // ---- backward (mirrored values) ----
    unsigned int maskb = mask;
    if (lane == 63) maskb &= ~(1u << 31);   // exclude j = L-1
    cnt = 0; va = 0; vb = 0;
#pragma unroll
    for (int tt = 31; tt >= 0; tt--) {
        if (maskb & (1u << tt)) { vb = va; va = (SEQ - 1) - (lane * 32 + tt); cnt++; }
    }
    summ[lane] = (unsigned)((cnt > 2 ? 2 : cnt) | (va << 2) | (vb << 13));
    __syncthreads();
    int a2 = SEQ - 1, b2 = SEQ - 1;
    for (int tt = 63; tt > lane; tt--) {
        unsigned s = summ[tt];
        int c = s & 3, sva = (s >> 2) & 2047, svb = (s >> 13) & 2047;
        if (c >= 2) { a2 = sva; b2 = svb; }
        else if (c == 1) { b2 = a2; a2 = sva; }
    }
#pragma unroll
    for (int tt = 31; tt >= 0; tt--) {
        int j = lane * 32 + tt;
        if (maskb & (1u << tt)) { b2 = a2; a2 = (SEQ - 1) - j; }
        unsigned f = fres[tt];
        maps[((size_t)b * SEQ + j) * NH + n] =
            make_ushort4((unsigned short)(f & 0xffffu), (unsigned short)(f >> 16),
                         (unsigned short)a2, (unsigned short)b2);
    }
}

// ---------------- gather + weighted sum (CV layout [M][1024]) ----------------
__global__ __launch_bounds__(256) void gather_kernel(const float* __restrict__ CV,
                                                     const ushort4* __restrict__ maps,
                                                     const float* __restrict__ bw,
                                                     float* __restrict__ out) {
    int bl = blockIdx.x;
    int t = threadIdx.x, n = t >> 4, q = t & 15;
    int b = bl >> 11;
    ushort4 m = maps[(size_t)bl * NH + n];
    const float4 w = *(const float4*)&bw[n * 4];
    size_t colbase = (size_t)(n * 64 + q * 4);
    size_t rowb = (size_t)b * SEQ;
    const float4 v0 = *(const float4*)&CV[(rowb + m.x) * HDIM + colbase];
    const float4 v1 = *(const float4*)&CV[(rowb + m.y) * HDIM + colbase];
    const float4 v2 = *(const float4*)&CV[(rowb + m.z) * HDIM + colbase];
    const float4 v3 = *(const float4*)&CV[(rowb + m.w) * HDIM + colbase];
    float4 o;
    o.x = w.x * v0.x + w.y * v1.x + w.z * v2.x + w.w * v3.x;
    o.y = w.x * v0.y + w.y * v1.y + w.z * v2.y + w.w * v3.y;
    o.z = w.x * v0.z + w.y * v1.z + w.z * v2.z + w.w * v3.z;
    o.w = w.x * v0.w + w.y * v1.w + w.z * v2.w + w.w * v3.w;
    *(float4*)&out[(size_t)bl * (NH * HD) + n * 64 + q * 4] = o;
}

// ---------------- launch ----------------
extern "C" void kernel_launch(void* const* d_in, const int* in_sizes, int n_in,
                              void* d_out, int out_size, void* d_ws, size_t ws_size,
                              hipStream_t stream) {
    (void)in_sizes; (void)n_in; (void)out_size; (void)ws_size;
    const float* hs  = (const float*)d_in[0];
    const float* K1w = (const float*)d_in[1];
    const float* K1b = (const float*)d_in[2];
    const float* V1w = (const float*)d_in[3];
    const float* V1b = (const float*)d_in[4];
    const float* bw  = (const float*)d_in[5];
    const float* RH  = (const float*)d_in[6];
    float* out = (float*)d_out;
    char* ws = (char*)d_ws;

    unsigned short* Abf  = (unsigned short*)(ws + OFF_A);
    unsigned short* Btbf = (unsigned short*)(ws + OFF_BT);
    int* fcnt = (int*)(ws + OFF_FCNT);
    int* flist = (int*)(ws + OFF_FLIST);
    float* bias  = (float*)(ws + OFF_BIAS);
    float* CV    = (float*)(ws + OFF_CV);
    unsigned char* valid = (unsigned char*)(ws + OFF_VALID);
    ushort4* maps = (ushort4*)(ws + OFF_MAPS);

    cvt_bias_kernel<<<8, 256, 0, stream>>>(K1b, V1b, bias, fcnt);
    cvt_hs_kernel<<<16384, 256, 0, stream>>>((const float4*)hs, (ushort4*)Abf);
    cvt_w_kernel<<<dim3(32, 32, 2), 256, 0, stream>>>(K1w, V1w, Btbf);
    gemm_kernel<<<dim3(N_COLS / 128, M_ROWS / 128), 256, 0, stream>>>(
        Abf, Btbf, bias, RH, CV, valid, fcnt, flist);
    refine_kernel<<<NH * GROUPS_PER_HEAD, 256, 0, stream>>>(
        hs, K1w, K1b, RH, fcnt, flist, valid);
    scan_kernel<<<BS * NH, 64, 0, stream>>>(valid, maps);
    gather_kernel<<<BS * SEQ, 256, 0, stream>>>(CV, maps, bw, out);
}